// Round 1
// baseline (7590.135 us; speedup 1.0000x reference)
//
#include <hip/hip_runtime.h>
#include <hip/hip_bf16.h>

// Problem constants
#define BB 512
#define TT 256
#define SS 64
#define II 32
#define HH 1024
#define K1 96            // S + I
#define NT_H 64          // H/16 n-tiles
#define KS1 3            // K1/32
#define KS2 32           // H/32
#define NT_S 4           // S/16

// Packed fragment counts (each fragment = 512 halves = 1KB)
#define W1P_ELEMS (NT_H * KS1 * 512)   // 98304
#define W2P_ELEMS (NT_H * KS2 * 512)   // 1048576
#define W3P_ELEMS (NT_S * KS2 * 512)   // 65536
#define PACK_TOTAL (W1P_ELEMS + W2P_ELEMS + W3P_ELEMS)  // 1212416

typedef _Float16 f16x8 __attribute__((ext_vector_type(8)));
typedef float f32x4 __attribute__((ext_vector_type(4)));

// ---------------------------------------------------------------------------
// Pack fp32 weights -> fp16 fragments in exact MFMA B-operand lane order.
// Fragment f covers (ntile, kstep); lane l holds B[k][n] for n = nt*16+(l&15),
// k = ks*32 + (l>>4)*8 + j, j=0..7 (contiguous 8 halves = 16B per lane).
// ---------------------------------------------------------------------------
__global__ void pack_weights(const float* __restrict__ W1,
                             const float* __restrict__ W2,
                             const float* __restrict__ W3,
                             _Float16* __restrict__ W1p,
                             _Float16* __restrict__ W2p,
                             _Float16* __restrict__ W3p)
{
    int idx = blockIdx.x * 256 + threadIdx.x;
    if (idx >= PACK_TOTAL) return;
    const float* src;
    _Float16* dst;
    int K, e;
    if (idx < W1P_ELEMS)                 { src = W1; dst = W1p; K = K1; e = idx; }
    else if (idx < W1P_ELEMS + W2P_ELEMS){ src = W2; dst = W2p; K = HH; e = idx - W1P_ELEMS; }
    else                                 { src = W3; dst = W3p; K = HH; e = idx - W1P_ELEMS - W2P_ELEMS; }
    int j    = e & 7;
    int lane = (e >> 3) & 63;
    int f    = e >> 9;
    int KSw  = K / 32;
    int nt   = f / KSw;
    int ks   = f - nt * KSw;
    int n    = nt * 16 + (lane & 15);
    int k    = ks * 32 + ((lane >> 4) << 3) + j;
    dst[e] = (_Float16)src[(size_t)n * K + k];
}

// ---------------------------------------------------------------------------
// LDS helpers — XOR swizzle ^((row&7)<<4) keeps ds_read_b128 at <=2-way banks.
// ---------------------------------------------------------------------------
__device__ __forceinline__ void st_h16(unsigned char* base, int pitch, int row, int col, _Float16 v) {
    int off = (row * pitch + col * 2) ^ ((row & 7) << 4);
    *(_Float16*)(base + off) = v;
}

__device__ __forceinline__ f16x8 ld_frag_lds(const unsigned char* base, int pitch, int row, int k0) {
    int off = (row * pitch + k0 * 2) ^ ((row & 7) << 4);
    uint4 u = *(const uint4*)(base + off);
    return __builtin_bit_cast(f16x8, u);
}

__device__ __forceinline__ f16x8 ldg_frag(const _Float16* __restrict__ p, int fragIdx, int lane) {
    const uint4* q = (const uint4*)(p + (size_t)fragIdx * 512) + lane;
    uint4 u = *q;
    return __builtin_bit_cast(f16x8, u);
}

__device__ __forceinline__ float sigmoidf_fast(float z) {
    return 1.0f / (1.0f + __expf(-z));
}

// ---------------------------------------------------------------------------
// Persistent per-batch-slice RNN. 32 blocks x 512 threads (8 waves).
// Each block owns 16 batch rows for all T steps; only __syncthreads() needed.
// ---------------------------------------------------------------------------
__global__ __launch_bounds__(512) void rnn_main(
    const float* __restrict__ x0, const float* __restrict__ u,
    const float* __restrict__ b1, const float* __restrict__ b2, const float* __restrict__ b3,
    const _Float16* __restrict__ W1p, const _Float16* __restrict__ W2p, const _Float16* __restrict__ W3p,
    float* __restrict__ out)
{
    __shared__ __align__(16) unsigned char sXC[16 * 256];    // x_cat: 16 rows x 128 halves (cols 0..95 used)
    __shared__ __align__(16) unsigned char sH1[16 * 2048];   // h1: 16 x 1024 fp16
    __shared__ __align__(16) unsigned char sH2[16 * 2048];   // h2: 16 x 1024 fp16
    __shared__ f32x4 sP3[NT_S * 64];                         // GEMM3 K-half partials

    const int tid  = threadIdx.x;
    const int lane = tid & 63;
    const int w    = tid >> 6;          // wave 0..7
    const int b0   = blockIdx.x * 16;
    const int col  = lane & 15;         // n / output col within tile
    const int g    = lane >> 4;         // k-group (input) / row-group (output)

    // Biases preloaded once: one value per lane per owned n-tile.
    float b1v[8], b2v[8];
    #pragma unroll
    for (int i = 0; i < 8; ++i) {
        b1v[i] = b1[(w * 8 + i) * 16 + col];
        b2v[i] = b2[(w * 8 + i) * 16 + col];
    }
    const int nt3 = w & 3;              // GEMM3 n-tile
    const int kh  = w >> 2;             // GEMM3 k-half
    const float b3v = b3[nt3 * 16 + col];

    // Initial state: x0 -> XCAT[:, 0:64], u[:,0,:] -> XCAT[:, 64:96]
    for (int e = tid; e < 16 * 64; e += 512) {
        int m = e >> 6, s = e & 63;
        st_h16(sXC, 256, m, s, (_Float16)x0[(size_t)(b0 + m) * SS + s]);
    }
    {
        int m = tid >> 5, i = tid & 31;
        st_h16(sXC, 256, m, 64 + i, (_Float16)u[((size_t)(b0 + m) * TT + 0) * II + i]);
    }
    __syncthreads();

    for (int t = 0; t < TT; ++t) {
        // ---------------- GEMM1: z1 = xcat @ W1^T ----------------
        f32x4 acc[8];
        #pragma unroll
        for (int i = 0; i < 8; ++i) acc[i] = (f32x4){0.f, 0.f, 0.f, 0.f};
        #pragma unroll
        for (int ks = 0; ks < KS1; ++ks) {
            f16x8 a = ld_frag_lds(sXC, 256, col, ks * 32 + g * 8);
            #pragma unroll
            for (int i = 0; i < 8; ++i) {
                f16x8 bf = ldg_frag(W1p, (w * 8 + i) * KS1 + ks, lane);
                acc[i] = __builtin_amdgcn_mfma_f32_16x16x32_f16(a, bf, acc[i], 0, 0, 0);
            }
        }
        #pragma unroll
        for (int i = 0; i < 8; ++i) {
            int n = (w * 8 + i) * 16 + col;
            #pragma unroll
            for (int r = 0; r < 4; ++r) {
                float h = sigmoidf_fast(acc[i][r] + b1v[i]);
                st_h16(sH1, 2048, g * 4 + r, n, (_Float16)h);
            }
        }
        __syncthreads();

        // u_{t+1} -> XCAT (XCAT free after GEMM1; overlaps GEMM2)
        if (t + 1 < TT) {
            int m = tid >> 5, i = tid & 31;
            st_h16(sXC, 256, m, 64 + i, (_Float16)u[((size_t)(b0 + m) * TT + (t + 1)) * II + i]);
        }

        // ---------------- GEMM2: z2 = h1 @ W2^T ----------------
        #pragma unroll
        for (int i = 0; i < 8; ++i) acc[i] = (f32x4){0.f, 0.f, 0.f, 0.f};
        #pragma unroll 2
        for (int ks = 0; ks < KS2; ++ks) {
            f16x8 a = ld_frag_lds(sH1, 2048, col, ks * 32 + g * 8);
            #pragma unroll
            for (int i = 0; i < 8; ++i) {
                f16x8 bf = ldg_frag(W2p, (w * 8 + i) * KS2 + ks, lane);
                acc[i] = __builtin_amdgcn_mfma_f32_16x16x32_f16(a, bf, acc[i], 0, 0, 0);
            }
        }
        #pragma unroll
        for (int i = 0; i < 8; ++i) {
            int n = (w * 8 + i) * 16 + col;
            #pragma unroll
            for (int r = 0; r < 4; ++r) {
                float h = sigmoidf_fast(acc[i][r] + b2v[i]);
                st_h16(sH2, 2048, g * 4 + r, n, (_Float16)h);
            }
        }
        __syncthreads();

        // ---------------- GEMM3: x' = h2 @ W3^T (split K in halves) --------
        f32x4 a3 = (f32x4){0.f, 0.f, 0.f, 0.f};
        #pragma unroll 4
        for (int ks = 0; ks < 16; ++ks) {
            int kk = kh * 16 + ks;
            f16x8 a = ld_frag_lds(sH2, 2048, col, kk * 32 + g * 8);
            f16x8 bf = ldg_frag(W3p, nt3 * KS2 + kk, lane);
            a3 = __builtin_amdgcn_mfma_f32_16x16x32_f16(a, bf, a3, 0, 0, 0);
        }
        if (w >= 4) sP3[nt3 * 64 + lane] = a3;
        __syncthreads();
        if (w < 4) {
            f32x4 p = sP3[nt3 * 64 + lane];
            #pragma unroll
            for (int r = 0; r < 4; ++r) {
                int m = g * 4 + r;
                float x = a3[r] + p[r] + b3v;
                out[((size_t)(b0 + m) * TT + t) * SS + nt3 * 16 + col] = x;
                st_h16(sXC, 256, m, nt3 * 16 + col, (_Float16)x);
            }
        }
        __syncthreads();
    }
}

// ---------------------------------------------------------------------------
extern "C" void kernel_launch(void* const* d_in, const int* in_sizes, int n_in,
                              void* d_out, int out_size, void* d_ws, size_t ws_size,
                              hipStream_t stream) {
    const float* x0 = (const float*)d_in[0];
    const float* u  = (const float*)d_in[1];
    const float* W1 = (const float*)d_in[2];
    const float* b1 = (const float*)d_in[3];
    const float* W2 = (const float*)d_in[4];
    const float* b2 = (const float*)d_in[5];
    const float* W3 = (const float*)d_in[6];
    const float* b3 = (const float*)d_in[7];
    float* out = (float*)d_out;

    _Float16* W1p = (_Float16*)d_ws;
    _Float16* W2p = W1p + W1P_ELEMS;
    _Float16* W3p = W2p + W2P_ELEMS;

    pack_weights<<<PACK_TOTAL / 256, 256, 0, stream>>>(W1, W2, W3, W1p, W2p, W3p);
    rnn_main<<<BB / 16, 512, 0, stream>>>(x0, u, b1, b2, b3, W1p, W2p, W3p, out);
}

// Round 3
// 4477.235 us; speedup vs baseline: 1.6953x; 1.6953x over previous
//
#include <hip/hip_runtime.h>
#include <hip/hip_bf16.h>

// Problem constants
#define BB 512
#define TT 256
#define SS 64
#define II 32
#define HH 1024
#define K1 96            // S + I
#define KS1 3            // K1/32
#define KS2 32           // H/32

// Packed fragment counts (each fragment = 512 halves = 1KB)
#define W1P_ELEMS (64 * KS1 * 512)   // 98304
#define W2P_ELEMS (64 * KS2 * 512)   // 1048576
#define W3P_ELEMS (4  * KS2 * 512)   // 65536
#define PACK_TOTAL (W1P_ELEMS + W2P_ELEMS + W3P_ELEMS)

// Grid decomposition: 256 blocks = 32 batch-groups (16 rows) x 8 H-groups (128 cols)
#define MBG 32
#define NBG 8

// d_ws layout (bytes)
#define OFF_W1P   0
#define OFF_W2P   (OFF_W1P + W1P_ELEMS*2)
#define OFF_W3P   (OFF_W2P + W2P_ELEMS*2)
#define OFF_H1G   (OFF_W3P + W3P_ELEMS*2)            // 32*16*1024 fp16 = 1MB
#define OFF_SLOTS (OFF_H1G + MBG*16*HH*2)            // 32*8*16*64 f32 = 1MB
#define OFF_H1FL  (OFF_SLOTS + MBG*NBG*16*64*4)
#define OFF_SLFL  (OFF_H1FL + 1024)

typedef _Float16 f16x8 __attribute__((ext_vector_type(8)));
typedef float f32x4 __attribute__((ext_vector_type(4)));
typedef unsigned long long u64;

// ---------------------------------------------------------------------------
// Pack fp32 weights -> fp16 fragments in exact MFMA B-operand lane order.
// (validated in R1)
// ---------------------------------------------------------------------------
__global__ void pack_weights(const float* __restrict__ W1,
                             const float* __restrict__ W2,
                             const float* __restrict__ W3,
                             _Float16* __restrict__ W1p,
                             _Float16* __restrict__ W2p,
                             _Float16* __restrict__ W3p)
{
    int idx = blockIdx.x * 256 + threadIdx.x;
    if (idx >= PACK_TOTAL) return;
    const float* src;
    _Float16* dst;
    int K, e;
    if (idx < W1P_ELEMS)                 { src = W1; dst = W1p; K = K1; e = idx; }
    else if (idx < W1P_ELEMS + W2P_ELEMS){ src = W2; dst = W2p; K = HH; e = idx - W1P_ELEMS; }
    else                                 { src = W3; dst = W3p; K = HH; e = idx - W1P_ELEMS - W2P_ELEMS; }
    int j    = e & 7;
    int lane = (e >> 3) & 63;
    int f    = e >> 9;
    int KSw  = K / 32;
    int nt   = f / KSw;
    int ks   = f - nt * KSw;
    int n    = nt * 16 + (lane & 15);
    int k    = ks * 32 + ((lane >> 4) << 3) + j;
    dst[e] = (_Float16)src[(size_t)n * K + k];
}

// ---------------------------------------------------------------------------
// LDS helpers — XOR swizzle ^((row&7)<<4): <=2-way bank access on b128 reads.
// 8B variants stay within a 16B swizzle unit (col multiple of 4 halves).
// ---------------------------------------------------------------------------
__device__ __forceinline__ void st_h16(unsigned char* base, int pitch, int row, int col, _Float16 v) {
    int off = (row * pitch + col * 2) ^ ((row & 7) << 4);
    *(_Float16*)(base + off) = v;
}
__device__ __forceinline__ void st_b128(unsigned char* base, int pitch, int row, int col, uint4 v) {
    int off = (row * pitch + col * 2) ^ ((row & 7) << 4);
    *(uint4*)(base + off) = v;
}
__device__ __forceinline__ uint4 ld_b128(const unsigned char* base, int pitch, int row, int col) {
    int off = (row * pitch + col * 2) ^ ((row & 7) << 4);
    return *(const uint4*)(base + off);
}
__device__ __forceinline__ void st_b64l(unsigned char* base, int pitch, int row, int col, u64 v) {
    int off = (row * pitch + col * 2) ^ ((row & 7) << 4);
    *(u64*)(base + off) = v;
}
__device__ __forceinline__ u64 ld_b64l(const unsigned char* base, int pitch, int row, int col) {
    int off = (row * pitch + col * 2) ^ ((row & 7) << 4);
    return *(const u64*)(base + off);
}
__device__ __forceinline__ f16x8 ld_frag_lds(const unsigned char* base, int pitch, int row, int k0) {
    return __builtin_bit_cast(f16x8, ld_b128(base, pitch, row, k0));
}
__device__ __forceinline__ f16x8 ldg_frag(const _Float16* __restrict__ p, int fragIdx, int lane) {
    const uint4* q = (const uint4*)(p + (size_t)fragIdx * 512) + lane;
    return __builtin_bit_cast(f16x8, *q);
}
__device__ __forceinline__ float sigmoidf_fast(float z) {
    return 1.0f / (1.0f + __expf(-z));
}

// Relaxed agent-scope accesses: emit sc0 sc1 (L1/L2-bypass, coherent at L3),
// NO bulk cache maintenance. Ordering comes from __syncthreads vmcnt-drain.
__device__ __forceinline__ u64 ldg_u64(const u64* p) {
    return __hip_atomic_load((u64*)p, __ATOMIC_RELAXED, __HIP_MEMORY_SCOPE_AGENT);
}
__device__ __forceinline__ void stg_u64(u64* p, u64 v) {
    __hip_atomic_store(p, v, __ATOMIC_RELAXED, __HIP_MEMORY_SCOPE_AGENT);
}
__device__ __forceinline__ void stg_f32(float* p, float v) {
    __hip_atomic_store(p, v, __ATOMIC_RELAXED, __HIP_MEMORY_SCOPE_AGENT);
}
__device__ __forceinline__ int ldg_flag(int* p) {
    return __hip_atomic_load(p, __ATOMIC_RELAXED, __HIP_MEMORY_SCOPE_AGENT);
}
__device__ __forceinline__ void stg_flag(int* p, int v) {
    __hip_atomic_store(p, v, __ATOMIC_RELAXED, __HIP_MEMORY_SCOPE_AGENT);
}

// Bounded spin: deadlock degrades to wrong-answer diagnostic, never a hang.
__device__ __forceinline__ void spin_ge(int* f, int target, volatile int* dead) {
    if (*dead) return;
    int it = 0;
    while (ldg_flag(f) < target) {
        __builtin_amdgcn_s_sleep(4);
        if (++it > 150000) { *dead = 1; break; }   // ~40ms escape hatch
    }
}

// ---------------------------------------------------------------------------
// Weight-stationary RNN. 256 blocks x 512 threads (regular launch; 8 waves x
// ~220 VGPR -> 1 block/CU -> all 256 blocks co-resident on 256 CUs).
// Block (mb, nb): mb = bid&31 (16 batch rows), nb = bid>>5 (128 H cols).
// W1/W2/W3 shares live in registers for all 256 steps (W2: 128 VGPR/lane).
// Per step: GEMM1(own stripe) -> h1 exchange within mb-group via L3 (relaxed
// sc0sc1 atomics + flags) -> GEMM2 (LDS h1[16][1024], reg W2) -> GEMM3
// partial -> f32 slot; next step's phase A gathers the 8 slots.
// Hazard proof: slotflag(t) follows peers' h1-read of t (WAW on h1g safe);
// h1flag(t+1) follows peers' slot-gather of t (WAR on slots safe).
// ---------------------------------------------------------------------------
__global__ __launch_bounds__(512, 2) void rnn_main(
    const float* __restrict__ x0, const float* __restrict__ u,
    const float* __restrict__ b1, const float* __restrict__ b2, const float* __restrict__ b3,
    const _Float16* __restrict__ W1p, const _Float16* __restrict__ W2p, const _Float16* __restrict__ W3p,
    _Float16* __restrict__ h1g, float* __restrict__ slots,
    int* __restrict__ h1flag, int* __restrict__ slotflag,
    float* __restrict__ out)
{
    __shared__ __align__(16) unsigned char sH1A[16 * 2048];  // h1 [16][1024] fp16, swizzled
    __shared__ __align__(16) unsigned char sXC [16 * 256];   // xcat [16][128] fp16
    __shared__ __align__(16) unsigned char sH2 [16 * 256];   // h2 [16][128] fp16
    __shared__ int sDead;

    const int tid  = threadIdx.x;
    const int lane = tid & 63;
    const int w    = tid >> 6;
    const int bid  = blockIdx.x;
    const int mb   = bid & 31;
    const int nb   = bid >> 5;
    const int b0   = mb * 16;
    const int col  = lane & 15;
    const int g    = lane >> 4;

    // Register-resident weights: W2 share = 128 VGPR/lane; W1 12; W3 16.
    const int nt = nb * 8 + w;
    f16x8 w1f[KS1], w2f[KS2], w3f[4];
    #pragma unroll
    for (int ks = 0; ks < KS1; ++ks) w1f[ks] = ldg_frag(W1p, nt * KS1 + ks, lane);
    #pragma unroll
    for (int ks = 0; ks < KS2; ++ks) w2f[ks] = ldg_frag(W2p, nt * KS2 + ks, lane);
    const int st = w & 3;
    #pragma unroll
    for (int ks = 0; ks < 4; ++ks) w3f[ks] = ldg_frag(W3p, st * KS2 + nb * 4 + ks, lane);
    const float b1v = b1[nt * 16 + col];
    const float b2v = b2[nt * 16 + col];

    const int gm = tid >> 3;            // gather row (tid<128)
    const int gs = (tid & 7) * 8;       // gather col start
    float b3v[8];
    #pragma unroll
    for (int i = 0; i < 8; ++i) b3v[i] = b3[(gs + i) & 63];

    int* myH1FL = h1flag + mb * 8;
    int* mySLFL = slotflag + mb * 8;
    u64* h1g64  = (u64*)h1g;

    if (tid == 0) sDead = 0;
    __syncthreads();

    for (int t = 0;; ++t) {
        // ---- phase A: spin slots(t-1) ready; gather -> out[t-1], xcat ----
        if (t > 0 && tid < 8) spin_ge(&mySLFL[tid], t, &sDead);
        __syncthreads();
        if (t == 0) {
            if (tid < 128) {
                const float* xp = x0 + (size_t)(b0 + gm) * SS + gs;
                float4 pa = *(const float4*)xp, pb = *(const float4*)(xp + 4);
                f16x8 pk;
                pk[0]=(_Float16)pa.x; pk[1]=(_Float16)pa.y; pk[2]=(_Float16)pa.z; pk[3]=(_Float16)pa.w;
                pk[4]=(_Float16)pb.x; pk[5]=(_Float16)pb.y; pk[6]=(_Float16)pb.z; pk[7]=(_Float16)pb.w;
                st_b128(sXC, 256, gm, gs, __builtin_bit_cast(uint4, pk));
            }
        } else {
            if (tid < 128) {
                float s0[8];
                #pragma unroll
                for (int i = 0; i < 8; ++i) s0[i] = b3v[i];
                #pragma unroll
                for (int nb2 = 0; nb2 < 8; ++nb2) {
                    const u64* sp = (const u64*)(slots + ((size_t)(mb * 8 + nb2) * 16 + gm) * 64 + gs);
                    #pragma unroll
                    for (int q = 0; q < 4; ++q) {
                        float2 f2 = __builtin_bit_cast(float2, ldg_u64(sp + q));
                        s0[q * 2 + 0] += f2.x;
                        s0[q * 2 + 1] += f2.y;
                    }
                }
                if (nb == 0) {
                    float* op = out + ((size_t)(b0 + gm) * TT + (t - 1)) * SS + gs;
                    *(float4*)op       = make_float4(s0[0], s0[1], s0[2], s0[3]);
                    *(float4*)(op + 4) = make_float4(s0[4], s0[5], s0[6], s0[7]);
                }
                if (t < TT) {
                    f16x8 pk;
                    #pragma unroll
                    for (int i = 0; i < 8; ++i) pk[i] = (_Float16)s0[i];
                    st_b128(sXC, 256, gm, gs, __builtin_bit_cast(uint4, pk));
                }
            }
        }
        if (t == TT) break;
        if (tid >= 128 && tid < 256) {       // u_t -> xcat cols 64..95
            int tr = tid - 128;
            int m = tr >> 3, i4 = tr & 7;
            const float* up = u + ((size_t)(b0 + m) * TT + t) * II + i4 * 4;
            float4 uv = *(const float4*)up;
            st_h16(sXC, 256, m, 64 + i4*4 + 0, (_Float16)uv.x);
            st_h16(sXC, 256, m, 64 + i4*4 + 1, (_Float16)uv.y);
            st_h16(sXC, 256, m, 64 + i4*4 + 2, (_Float16)uv.z);
            st_h16(sXC, 256, m, 64 + i4*4 + 3, (_Float16)uv.w);
        }
        __syncthreads();

        // ---- GEMM1: h1 stripe (own 128 cols) ----
        f32x4 a1 = (f32x4){0.f, 0.f, 0.f, 0.f};
        #pragma unroll
        for (int ks = 0; ks < KS1; ++ks)
            a1 = __builtin_amdgcn_mfma_f32_16x16x32_f16(
                     ld_frag_lds(sXC, 256, col, ks * 32 + g * 8), w1f[ks], a1, 0, 0, 0);
        #pragma unroll
        for (int r = 0; r < 4; ++r)
            st_h16(sH1A, 2048, g * 4 + r, nb * 128 + w * 16 + col,
                   (_Float16)sigmoidf_fast(a1[r] + b1v));
        __syncthreads();

        // ---- own stripe -> L3; flag; peers' stripes -> LDS ----
        {
            int row = tid >> 5, c8 = tid & 31;
            u64 v = ld_b64l(sH1A, 2048, row, nb * 128 + c8 * 4);
            stg_u64(h1g64 + (size_t)(mb * 16 + row) * 256 + nb * 32 + c8, v);
        }
        __syncthreads();   // vmcnt(0) drain: stripe stores complete at L3
        if (tid == 0) stg_flag(&myH1FL[nb], t + 1);
        if (tid < 8) spin_ge(&myH1FL[tid], t + 1, &sDead);
        __syncthreads();
        #pragma unroll
        for (int sIdx = 0; sIdx < 7; ++sIdx) {
            int nbp = sIdx + (sIdx >= nb);
            int row = tid >> 5, c8 = tid & 31;
            u64 v = ldg_u64(h1g64 + (size_t)(mb * 16 + row) * 256 + nbp * 32 + c8);
            st_b64l(sH1A, 2048, row, nbp * 128 + c8 * 4, v);
        }
        __syncthreads();

        // ---- GEMM2: z2[16 x own 16 cols] over K=1024, W2 in registers ----
        f32x4 a2 = (f32x4){0.f, 0.f, 0.f, 0.f};
        #pragma unroll
        for (int ks = 0; ks < KS2; ++ks)
            a2 = __builtin_amdgcn_mfma_f32_16x16x32_f16(
                     ld_frag_lds(sH1A, 2048, col, ks * 32 + g * 8), w2f[ks], a2, 0, 0, 0);
        #pragma unroll
        for (int r = 0; r < 4; ++r)
            st_h16(sH2, 256, g * 4 + r, w * 16 + col,
                   (_Float16)sigmoidf_fast(a2[r] + b2v));
        __syncthreads();

        // ---- GEMM3 partial (K = own 128 h2 cols), waves 0..3 ----
        if (w < 4) {
            f32x4 a3 = (f32x4){0.f, 0.f, 0.f, 0.f};
            #pragma unroll
            for (int ksl = 0; ksl < 4; ++ksl)
                a3 = __builtin_amdgcn_mfma_f32_16x16x32_f16(
                         ld_frag_lds(sH2, 256, col, ksl * 32 + g * 8), w3f[ksl], a3, 0, 0, 0);
            #pragma unroll
            for (int r = 0; r < 4; ++r)
                stg_f32(&slots[((size_t)(mb * 8 + nb) * 16 + g * 4 + r) * 64 + st * 16 + col], a3[r]);
        }
        __syncthreads();   // vmcnt(0) drain: slot stores complete at L3
        if (tid == 0) stg_flag(&mySLFL[nb], t + 1);
    }
}

// ---------------------------------------------------------------------------
extern "C" void kernel_launch(void* const* d_in, const int* in_sizes, int n_in,
                              void* d_out, int out_size, void* d_ws, size_t ws_size,
                              hipStream_t stream) {
    const float* x0 = (const float*)d_in[0];
    const float* u  = (const float*)d_in[1];
    const float* W1 = (const float*)d_in[2];
    const float* b1 = (const float*)d_in[3];
    const float* W2 = (const float*)d_in[4];
    const float* b2 = (const float*)d_in[5];
    const float* W3 = (const float*)d_in[6];
    const float* b3 = (const float*)d_in[7];
    float* out = (float*)d_out;

    char* ws = (char*)d_ws;
    _Float16* W1p  = (_Float16*)(ws + OFF_W1P);
    _Float16* W2p  = (_Float16*)(ws + OFF_W2P);
    _Float16* W3p  = (_Float16*)(ws + OFF_W3P);
    _Float16* h1g  = (_Float16*)(ws + OFF_H1G);
    float*    slots= (float*)   (ws + OFF_SLOTS);
    int*      h1fl = (int*)     (ws + OFF_H1FL);
    int*      slfl = (int*)     (ws + OFF_SLFL);

    hipMemsetAsync(ws + OFF_H1FL, 0, 2048, stream);
    pack_weights<<<(PACK_TOTAL + 255) / 256, 256, 0, stream>>>(W1, W2, W3, W1p, W2p, W3p);
    rnn_main<<<MBG * NBG, 512, 0, stream>>>(x0, u, b1, b2, b3, W1p, W2p, W3p,
                                            h1g, slots, h1fl, slfl, out);
}